// Round 1
// baseline (105.044 us; speedup 1.0000x reference)
//
#include <hip/hip_runtime.h>

#define NCH   1024   // IN_CH
#define ZDIM  128
#define NZ    1024   // FEAT*FEAT
#define KOUT  72     // OUT_CH * F_SIZE * F_SIZE

__global__ __launch_bounds__(256, 4) void hyper_fused_kernel(
    const float* __restrict__ z,      // (NCH, NZ)
    const float* __restrict__ W_in,   // (NCH, ZDIM, NZ)
    const float* __restrict__ b_in,   // (NCH, ZDIM)
    const float* __restrict__ W_out,  // (KOUT, ZDIM)
    const float* __restrict__ b_out,  // (KOUT)
    float* __restrict__ out)          // (8, NCH, 3, 3) flat
{
    __shared__ float xs[NZ];     // this channel's flattened latent
    __shared__ float as[ZDIM];   // this channel's hidden activation

    const int c    = blockIdx.x;
    const int tid  = threadIdx.x;
    const int lane = tid & 63;
    const int wave = tid >> 6;

    // ---- stage 0: load x[c] (1024 f32) into LDS, one float4/thread ----
    const float4* zp  = (const float4*)(z + (size_t)c * NZ);
    float4*       xs4 = (float4*)xs;
    xs4[tid] = zp[tid];
    __syncthreads();

    // ---- stage 1: a[d] = W_in[c,d,:] . x + b_in[c,d] ----
    // wave w handles d in [w*32, w*32+32); per d: 64 lanes x 4 float4 coalesced
    const float4* Wc = (const float4*)(W_in + (size_t)c * ZDIM * NZ);
    for (int dd = 0; dd < 32; ++dd) {
        const int d = wave * 32 + dd;
        const float4* row = Wc + (size_t)d * (NZ / 4);
        float sum = 0.f;
        #pragma unroll
        for (int k = 0; k < 4; ++k) {
            const float4 wv = row[lane + 64 * k];
            const float4 xv = xs4[lane + 64 * k];
            sum += wv.x * xv.x + wv.y * xv.y + wv.z * xv.z + wv.w * xv.w;
        }
        #pragma unroll
        for (int off = 32; off > 0; off >>= 1)
            sum += __shfl_xor(sum, off, 64);
        if (lane == 0)
            as[d] = sum + b_in[c * ZDIM + d];
    }
    __syncthreads();

    // ---- stage 2: k[c,t] = a . W_out[t,:] + b_out[t], transposed store ----
    if (tid < KOUT) {
        const float4* wr = (const float4*)(W_out + tid * ZDIM);
        const float4* av = (const float4*)as;
        float sum = 0.f;
        #pragma unroll
        for (int j = 0; j < ZDIM / 4; ++j) {
            const float4 w = wr[j];
            const float4 a = av[j];
            sum += w.x * a.x + w.y * a.y + w.z * a.z + w.w * a.w;
        }
        sum += b_out[tid];
        const int o = tid / 9;
        const int r = tid % 9;
        out[(size_t)o * (NCH * 9) + (size_t)c * 9 + r] = sum;
    }
}

extern "C" void kernel_launch(void* const* d_in, const int* in_sizes, int n_in,
                              void* d_out, int out_size, void* d_ws, size_t ws_size,
                              hipStream_t stream) {
    const float* z     = (const float*)d_in[0];
    const float* W_in  = (const float*)d_in[1];
    const float* b_in  = (const float*)d_in[2];
    const float* W_out = (const float*)d_in[3];
    const float* b_out = (const float*)d_in[4];
    float* out = (float*)d_out;

    hyper_fused_kernel<<<NCH, 256, 0, stream>>>(z, W_in, b_in, W_out, b_out, out);
}

// Round 3
// 96.630 us; speedup vs baseline: 1.0871x; 1.0871x over previous
//
#include <hip/hip_runtime.h>

#define NCH   1024   // IN_CH
#define ZDIM  128
#define NZ    1024   // FEAT*FEAT
#define KOUT  72     // OUT_CH * F_SIZE * F_SIZE

typedef float f4 __attribute__((ext_vector_type(4)));

__device__ __forceinline__ float dot4(f4 a, f4 b) {
    return a.x * b.x + a.y * b.y + a.z * b.z + a.w * b.w;
}

__global__ __launch_bounds__(256, 4) void hyper_fused_kernel(
    const float* __restrict__ z,      // (NCH, NZ)
    const float* __restrict__ W_in,   // (NCH, ZDIM, NZ)
    const float* __restrict__ b_in,   // (NCH, ZDIM)
    const float* __restrict__ W_out,  // (KOUT, ZDIM)
    const float* __restrict__ b_out,  // (KOUT)
    float* __restrict__ out)          // (8, NCH, 3, 3) flat
{
    __shared__ float as[ZDIM];   // hidden activation a[c,:]

    const int c    = blockIdx.x;
    const int tid  = threadIdx.x;
    const int lane = tid & 63;
    const int wave = tid >> 6;

    // ---- register-cache this lane's slice of x[c] (reused by all 32 rows) ----
    const f4* zp = (const f4*)(z + (size_t)c * NZ);
    const f4 xv0 = zp[lane];
    const f4 xv1 = zp[lane + 64];
    const f4 xv2 = zp[lane + 128];
    const f4 xv3 = zp[lane + 192];

    // ---- stage 1: a[d] = W_in[c,d,:] . x + b_in[c,d], 2 rows / iteration ----
    const f4* Wc = (const f4*)(W_in + (size_t)c * ZDIM * NZ);
    const float* bc = b_in + c * ZDIM;

    for (int dd = 0; dd < 32; dd += 2) {
        const int d0 = wave * 32 + dd;
        const f4* r0 = Wc + (size_t)d0 * (NZ / 4) + lane;
        const f4* r1 = r0 + (NZ / 4);

        const f4 a0 = __builtin_nontemporal_load(r0);
        const f4 a1 = __builtin_nontemporal_load(r0 + 64);
        const f4 a2 = __builtin_nontemporal_load(r0 + 128);
        const f4 a3 = __builtin_nontemporal_load(r0 + 192);
        const f4 b0 = __builtin_nontemporal_load(r1);
        const f4 b1 = __builtin_nontemporal_load(r1 + 64);
        const f4 b2 = __builtin_nontemporal_load(r1 + 128);
        const f4 b3 = __builtin_nontemporal_load(r1 + 192);

        float s0 = dot4(a0, xv0) + dot4(a1, xv1) + dot4(a2, xv2) + dot4(a3, xv3);
        float s1 = dot4(b0, xv0) + dot4(b1, xv1) + dot4(b2, xv2) + dot4(b3, xv3);

        // paired reduce: 7 shuffles for 2 rows
        float t0 = s0 + __shfl_xor(s0, 32, 64);
        float t1 = s1 + __shfl_xor(s1, 32, 64);
        float u  = (lane < 32) ? t0 : t1;   // halves carry row d0 / row d0+1
        u += __shfl_xor(u, 16, 64);
        u += __shfl_xor(u, 8, 64);
        u += __shfl_xor(u, 4, 64);
        u += __shfl_xor(u, 2, 64);
        u += __shfl_xor(u, 1, 64);

        if (lane == 0)  as[d0]     = u + bc[d0];
        if (lane == 32) as[d0 + 1] = u + bc[d0 + 1];
    }
    __syncthreads();

    // ---- stage 2: k[c,t] = a . W_out[t,:] + b_out[t], transposed store ----
    if (tid < KOUT) {
        const f4* wr = (const f4*)(W_out + tid * ZDIM);
        const f4* av = (const f4*)as;
        float sum = 0.f;
        #pragma unroll
        for (int j = 0; j < ZDIM / 4; ++j)
            sum += dot4(wr[j], av[j]);
        sum += b_out[tid];
        const int o = tid / 9;
        const int r = tid % 9;
        out[(size_t)o * (NCH * 9) + (size_t)c * 9 + r] = sum;
    }
}

extern "C" void kernel_launch(void* const* d_in, const int* in_sizes, int n_in,
                              void* d_out, int out_size, void* d_ws, size_t ws_size,
                              hipStream_t stream) {
    const float* z     = (const float*)d_in[0];
    const float* W_in  = (const float*)d_in[1];
    const float* b_in  = (const float*)d_in[2];
    const float* W_out = (const float*)d_in[3];
    const float* b_out = (const float*)d_in[4];
    float* out = (float*)d_out;

    hyper_fused_kernel<<<NCH, 256, 0, stream>>>(z, W_in, b_in, W_out, b_out, out);
}

// Round 4
// 93.419 us; speedup vs baseline: 1.1244x; 1.0344x over previous
//
#include <hip/hip_runtime.h>

#define NCH   1024   // IN_CH
#define ZDIM  128
#define NZ    1024   // FEAT*FEAT
#define KOUT  72     // OUT_CH * F_SIZE * F_SIZE

typedef float f4 __attribute__((ext_vector_type(4)));

__device__ __forceinline__ float dot4(f4 a, f4 b) {
    return a.x * b.x + a.y * b.y + a.z * b.z + a.w * b.w;
}

// 512 threads = 8 waves; wave w owns d-rows [w*16, w*16+16).
// __launch_bounds__(512, 8): force <=64 VGPR so 4 blocks/CU = 32 waves/CU.
__global__ __launch_bounds__(512, 8) void hyper_fused_kernel(
    const float* __restrict__ z,      // (NCH, NZ)
    const float* __restrict__ W_in,   // (NCH, ZDIM, NZ)
    const float* __restrict__ b_in,   // (NCH, ZDIM)
    const float* __restrict__ W_out,  // (KOUT, ZDIM)
    const float* __restrict__ b_out,  // (KOUT)
    float* __restrict__ out)          // (8, NCH, 3, 3) flat
{
    __shared__ float as[ZDIM];   // hidden activation a[c,:]

    const int c    = blockIdx.x;
    const int tid  = threadIdx.x;
    const int lane = tid & 63;
    const int wave = tid >> 6;

    // ---- register-cache this lane's slice of x[c] (reused by all 16 rows) ----
    const f4* zp = (const f4*)(z + (size_t)c * NZ);
    const f4 xv0 = zp[lane];
    const f4 xv1 = zp[lane + 64];
    const f4 xv2 = zp[lane + 128];
    const f4 xv3 = zp[lane + 192];

    // ---- stage 1: a[d] = W_in[c,d,:] . x + b_in[c,d], 2 rows / iteration ----
    const f4* Wc = (const f4*)(W_in + (size_t)c * ZDIM * NZ);
    const float* bc = b_in + c * ZDIM;

    for (int dd = 0; dd < 16; dd += 2) {
        const int d0 = wave * 16 + dd;
        const f4* r0 = Wc + (size_t)d0 * (NZ / 4) + lane;
        const f4* r1 = r0 + (NZ / 4);

        const f4 a0 = __builtin_nontemporal_load(r0);
        const f4 a1 = __builtin_nontemporal_load(r0 + 64);
        const f4 a2 = __builtin_nontemporal_load(r0 + 128);
        const f4 a3 = __builtin_nontemporal_load(r0 + 192);
        const f4 b0 = __builtin_nontemporal_load(r1);
        const f4 b1 = __builtin_nontemporal_load(r1 + 64);
        const f4 b2 = __builtin_nontemporal_load(r1 + 128);
        const f4 b3 = __builtin_nontemporal_load(r1 + 192);

        float s0 = dot4(a0, xv0) + dot4(a1, xv1) + dot4(a2, xv2) + dot4(a3, xv3);
        float s1 = dot4(b0, xv0) + dot4(b1, xv1) + dot4(b2, xv2) + dot4(b3, xv3);

        // paired reduce: 7 shuffles for 2 rows
        float t0 = s0 + __shfl_xor(s0, 32, 64);
        float t1 = s1 + __shfl_xor(s1, 32, 64);
        float u  = (lane < 32) ? t0 : t1;   // halves carry row d0 / row d0+1
        u += __shfl_xor(u, 16, 64);
        u += __shfl_xor(u, 8, 64);
        u += __shfl_xor(u, 4, 64);
        u += __shfl_xor(u, 2, 64);
        u += __shfl_xor(u, 1, 64);

        if (lane == 0)  as[d0]     = u + bc[d0];
        if (lane == 32) as[d0 + 1] = u + bc[d0 + 1];
    }
    __syncthreads();

    // ---- stage 2: k[c,t] = a . W_out[t,:] + b_out[t], transposed store ----
    if (tid < KOUT) {
        const f4* wr = (const f4*)(W_out + tid * ZDIM);
        const f4* av = (const f4*)as;
        float sum = 0.f;
        #pragma unroll
        for (int j = 0; j < ZDIM / 4; ++j)
            sum += dot4(wr[j], av[j]);
        sum += b_out[tid];
        const int o = tid / 9;
        const int r = tid % 9;
        out[(size_t)o * (NCH * 9) + (size_t)c * 9 + r] = sum;
    }
}

extern "C" void kernel_launch(void* const* d_in, const int* in_sizes, int n_in,
                              void* d_out, int out_size, void* d_ws, size_t ws_size,
                              hipStream_t stream) {
    const float* z     = (const float*)d_in[0];
    const float* W_in  = (const float*)d_in[1];
    const float* b_in  = (const float*)d_in[2];
    const float* W_out = (const float*)d_in[3];
    const float* b_out = (const float*)d_in[4];
    float* out = (float*)d_out;

    hyper_fused_kernel<<<NCH, 512, 0, stream>>>(z, W_in, b_in, W_out, b_out, out);
}